// Round 1
// baseline (77.840 us; speedup 1.0000x reference)
//
#include <hip/hip_runtime.h>

#define IN_F  1024
#define HID_F 1024
#define OUT_F 512
#define BATCH 128
#define NCHUNK1 16   // i-chunks for layer 1 (chunk = 64 i)
#define NCHUNK2 16   // j-chunks for layer 2 (chunk = 64 j)

__device__ __forceinline__ float sigm(float v) {
    return 1.0f / (1.0f + __expf(-v));
}

// K0: transpose x[128][1024] -> xt[1024][128] so layer-1 batch reads are
// contiguous wave-uniform scalar loads.
__global__ void k0_transpose_x(const float* __restrict__ x, float* __restrict__ xt) {
    __shared__ float tile[32][33];
    int i0 = blockIdx.x * 32;   // 32 blocks over IN_F
    int b0 = blockIdx.y * 32;   // 4 blocks over BATCH
    int tx = threadIdx.x;       // 0..31
    int ty = threadIdx.y;       // 0..7
#pragma unroll
    for (int r = 0; r < 32; r += 8)
        tile[ty + r][tx] = x[(b0 + ty + r) * IN_F + i0 + tx];
    __syncthreads();
#pragma unroll
    for (int r = 0; r < 32; r += 8)
        xt[(i0 + ty + r) * BATCH + b0 + tx] = tile[tx][ty + r];
}

// K1: layer-1 partial products over an i-chunk of 64.
// term = 1 - w + w*xnor = A + x*C,  A = 1 - w*s,  C = w*(2s-1)
// grid (4 j-tiles, 4 b-tiles, 16 i-chunks), block 256 (lane -> j, coalesced).
__global__ void k1_layer1(const float* __restrict__ w1, const float* __restrict__ s1,
                          const float* __restrict__ xt, float* __restrict__ P) {
    const int j  = blockIdx.x * 256 + threadIdx.x;
    const int b0 = blockIdx.y * 32;
    const int i0 = blockIdx.z * 64;
    float acc[32];
#pragma unroll
    for (int b = 0; b < 32; ++b) acc[b] = 1.0f;
    for (int ii = 0; ii < 64; ++ii) {
        const int i = i0 + ii;
        const float w = sigm(w1[i * HID_F + j]);
        const float s = sigm(s1[i * HID_F + j]);
        const float A = 1.0f - w * s;
        const float C = w * (2.0f * s - 1.0f);
        const float* __restrict__ xr = xt + i * BATCH + b0;  // wave-uniform -> s_load
#pragma unroll
        for (int b = 0; b < 32; ++b)
            acc[b] *= fmaf(xr[b], C, A);
    }
    float* Pp = P + blockIdx.z * (BATCH * HID_F) + b0 * HID_F + j;
#pragma unroll
    for (int b = 0; b < 32; ++b)
        Pp[b * HID_F] = acc[b];
}

// K2: combine 16 partial products -> h, stored transposed ht[j][b].
// grid (32 j-tiles, 4 b-tiles), block (32, 8).
__global__ void k2_combine_h(const float* __restrict__ P, float* __restrict__ ht) {
    __shared__ float tile[32][33];
    const int j0 = blockIdx.x * 32;
    const int b0 = blockIdx.y * 32;
    const int tx = threadIdx.x;  // j within tile
    const int ty = threadIdx.y;  // 0..7
#pragma unroll
    for (int r = 0; r < 32; r += 8) {
        const int b = b0 + ty + r;
        float acc = 1.0f;
#pragma unroll
        for (int ic = 0; ic < NCHUNK1; ++ic)
            acc *= P[ic * (BATCH * HID_F) + b * HID_F + j0 + tx];
        tile[ty + r][tx] = acc;
    }
    __syncthreads();
#pragma unroll
    for (int r = 0; r < 32; r += 8)
        ht[(j0 + ty + r) * BATCH + b0 + tx] = tile[tx][ty + r];
}

// K3: layer-2 partial products over a j-chunk of 64.
// term = 1 - sigm(w2[j,o]) * h[b,j]
// grid (2 o-tiles, 8 b-tiles, 16 j-chunks), block 256 (lane -> o, coalesced).
__global__ void k3_layer2(const float* __restrict__ w2, const float* __restrict__ ht,
                          float* __restrict__ Q) {
    const int o  = blockIdx.x * 256 + threadIdx.x;
    const int b0 = blockIdx.y * 16;
    const int j0 = blockIdx.z * 64;
    float acc[16];
#pragma unroll
    for (int b = 0; b < 16; ++b) acc[b] = 1.0f;
    for (int jj = 0; jj < 64; ++jj) {
        const int j = j0 + jj;
        const float wv = sigm(w2[j * OUT_F + o]);
        const float* __restrict__ hr = ht + j * BATCH + b0;  // wave-uniform -> s_load
#pragma unroll
        for (int b = 0; b < 16; ++b)
            acc[b] *= fmaf(-wv, hr[b], 1.0f);
    }
    float* Qp = Q + blockIdx.z * (BATCH * OUT_F) + b0 * OUT_F + o;
#pragma unroll
    for (int b = 0; b < 16; ++b)
        Qp[b * OUT_F] = acc[b];
}

// K4: final combine: out[b,o] = 1 - prod_chunks Q
__global__ void k4_final(const float* __restrict__ Q, float* __restrict__ out) {
    const int g = blockIdx.x * 256 + threadIdx.x;
    float acc = 1.0f;
#pragma unroll
    for (int ic = 0; ic < NCHUNK2; ++ic)
        acc *= Q[ic * (BATCH * OUT_F) + g];
    out[g] = 1.0f - acc;
}

extern "C" void kernel_launch(void* const* d_in, const int* in_sizes, int n_in,
                              void* d_out, int out_size, void* d_ws, size_t ws_size,
                              hipStream_t stream) {
    const float* x  = (const float*)d_in[0];
    const float* w1 = (const float*)d_in[1];
    const float* s1 = (const float*)d_in[2];
    const float* w2 = (const float*)d_in[3];
    float* out = (float*)d_out;

    // workspace layout (floats): xt 128K | ht 128K | P 2M | Q 1M  = 13 MB
    float* xt = (float*)d_ws;
    float* ht = xt + (size_t)IN_F * BATCH;
    float* P  = ht + (size_t)HID_F * BATCH;
    float* Q  = P + (size_t)NCHUNK1 * BATCH * HID_F;

    k0_transpose_x<<<dim3(IN_F / 32, BATCH / 32), dim3(32, 8), 0, stream>>>(x, xt);
    k1_layer1<<<dim3(HID_F / 256, BATCH / 32, NCHUNK1), 256, 0, stream>>>(w1, s1, xt, P);
    k2_combine_h<<<dim3(HID_F / 32, BATCH / 32), dim3(32, 8), 0, stream>>>(P, ht);
    k3_layer2<<<dim3(OUT_F / 256, BATCH / 16, NCHUNK2), 256, 0, stream>>>(w2, ht, Q);
    k4_final<<<(BATCH * OUT_F) / 256, 256, 0, stream>>>(Q, out);
}

// Round 2
// 68.147 us; speedup vs baseline: 1.1422x; 1.1422x over previous
//
#include <hip/hip_runtime.h>

#define IN_F  1024
#define HID_F 1024
#define OUT_F 512
#define BATCH 128
#define NCHUNK1 32   // i-chunks for layer 1 (chunk = 32 i)
#define NCHUNK2 32   // j-chunks for layer 2 (chunk = 32 j)

__device__ __forceinline__ float sigm(float v) {
    return 1.0f / (1.0f + __expf(-v));
}

// kPre: fused preprocessing.
//  blocks [0,1024):    AC[i][j] = (A,C) interleaved; A=1-w*s, C=w*(2s-1)
//  blocks [1024,1536): w2s = sigm(w2)
//  blocks [1536,1664): transpose x[128][1024] -> xt[1024][128]
__global__ __launch_bounds__(256) void kPre(const float* __restrict__ x,
                                            const float* __restrict__ w1,
                                            const float* __restrict__ s1,
                                            const float* __restrict__ w2,
                                            float* __restrict__ xt,
                                            float* __restrict__ AC,
                                            float* __restrict__ w2s) {
    const int bx = blockIdx.x;
    const int tid = threadIdx.x;
    if (bx < 1024) {
        const int e = (bx * 256 + tid) * 4;
        const float4 wv = *(const float4*)(w1 + e);
        const float4 sv = *(const float4*)(s1 + e);
        float w0 = sigm(wv.x), s0 = sigm(sv.x);
        float w1_ = sigm(wv.y), s1_ = sigm(sv.y);
        float w2_ = sigm(wv.z), s2_ = sigm(sv.z);
        float w3 = sigm(wv.w), s3 = sigm(sv.w);
        float4 lo, hi;
        lo.x = 1.0f - w0 * s0;  lo.y = w0 * (2.0f * s0 - 1.0f);
        lo.z = 1.0f - w1_ * s1_; lo.w = w1_ * (2.0f * s1_ - 1.0f);
        hi.x = 1.0f - w2_ * s2_; hi.y = w2_ * (2.0f * s2_ - 1.0f);
        hi.z = 1.0f - w3 * s3;  hi.w = w3 * (2.0f * s3 - 1.0f);
        *(float4*)(AC + 2 * e) = lo;
        *(float4*)(AC + 2 * e + 4) = hi;
    } else if (bx < 1536) {
        const int e = ((bx - 1024) * 256 + tid) * 4;
        const float4 wv = *(const float4*)(w2 + e);
        float4 r;
        r.x = sigm(wv.x); r.y = sigm(wv.y); r.z = sigm(wv.z); r.w = sigm(wv.w);
        *(float4*)(w2s + e) = r;
    } else {
        __shared__ float tile[32][33];
        const int bt = bx - 1536;
        const int i0 = (bt & 31) * 32;
        const int b0 = (bt >> 5) * 32;
        const int tx = tid & 31;
        const int ty = tid >> 5;   // 0..7
#pragma unroll
        for (int r = 0; r < 32; r += 8)
            tile[ty + r][tx] = x[(b0 + ty + r) * IN_F + i0 + tx];
        __syncthreads();
#pragma unroll
        for (int r = 0; r < 32; r += 8)
            xt[(i0 + ty + r) * BATCH + b0 + tx] = tile[tx][ty + r];
    }
}

// K1: layer-1 partial products over an i-chunk of 32.
// grid (4 j-tiles, 4 b-tiles(32), 32 i-chunks) = 512 blocks, lane -> j coalesced.
__global__ __launch_bounds__(256) void k1_layer1(const float* __restrict__ AC,
                                                 const float* __restrict__ xt,
                                                 float* __restrict__ P) {
    const int j  = blockIdx.x * 256 + threadIdx.x;
    const int b0 = blockIdx.y * 32;
    const int i0 = blockIdx.z * (IN_F / NCHUNK1);
    float acc[32];
#pragma unroll
    for (int b = 0; b < 32; ++b) acc[b] = 1.0f;
#pragma unroll 4
    for (int ii = 0; ii < IN_F / NCHUNK1; ++ii) {
        const int i = i0 + ii;
        const float2 ac = *(const float2*)(AC + 2 * (i * HID_F + j));
        const float* __restrict__ xr = xt + i * BATCH + b0;  // wave-uniform -> s_load
#pragma unroll
        for (int b = 0; b < 32; ++b)
            acc[b] *= fmaf(xr[b], ac.y, ac.x);
    }
    float* Pp = P + blockIdx.z * (BATCH * HID_F) + b0 * HID_F + j;
#pragma unroll
    for (int b = 0; b < 32; ++b)
        Pp[b * HID_F] = acc[b];
}

// K2: combine NCHUNK1 partial products -> h, stored transposed ht[j][b].
// grid (32 j-tiles, 4 b-tiles), block (32,8).
__global__ __launch_bounds__(256) void k2_combine_h(const float* __restrict__ P,
                                                    float* __restrict__ ht) {
    __shared__ float tile[32][33];
    const int j0 = blockIdx.x * 32;
    const int b0 = blockIdx.y * 32;
    const int tx = threadIdx.x & 31;
    const int ty = threadIdx.x >> 5;  // 0..7
#pragma unroll
    for (int r = 0; r < 32; r += 8) {
        const int b = b0 + ty + r;
        float acc = 1.0f;
#pragma unroll
        for (int ic = 0; ic < NCHUNK1; ++ic)
            acc *= P[ic * (BATCH * HID_F) + b * HID_F + j0 + tx];
        tile[ty + r][tx] = acc;
    }
    __syncthreads();
#pragma unroll
    for (int r = 0; r < 32; r += 8)
        ht[(j0 + ty + r) * BATCH + b0 + tx] = tile[tx][ty + r];
}

// K3: layer-2 partial products over a j-chunk of 32.
// grid (2 o-tiles, 8 b-tiles(16), 32 j-chunks) = 512 blocks, lane -> o coalesced.
__global__ __launch_bounds__(256) void k3_layer2(const float* __restrict__ w2s,
                                                 const float* __restrict__ ht,
                                                 float* __restrict__ Q) {
    const int o  = blockIdx.x * 256 + threadIdx.x;
    const int b0 = blockIdx.y * 16;
    const int j0 = blockIdx.z * (HID_F / NCHUNK2);
    float acc[16];
#pragma unroll
    for (int b = 0; b < 16; ++b) acc[b] = 1.0f;
#pragma unroll 4
    for (int jj = 0; jj < HID_F / NCHUNK2; ++jj) {
        const int j = j0 + jj;
        const float wv = w2s[j * OUT_F + o];
        const float* __restrict__ hr = ht + j * BATCH + b0;  // wave-uniform -> s_load
#pragma unroll
        for (int b = 0; b < 16; ++b)
            acc[b] *= fmaf(-wv, hr[b], 1.0f);
    }
    float* Qp = Q + blockIdx.z * (BATCH * OUT_F) + b0 * OUT_F + o;
#pragma unroll
    for (int b = 0; b < 16; ++b)
        Qp[b * OUT_F] = acc[b];
}

// K4: final combine: out[b,o] = 1 - prod_chunks Q
__global__ __launch_bounds__(256) void k4_final(const float* __restrict__ Q,
                                                float* __restrict__ out) {
    const int g = blockIdx.x * 256 + threadIdx.x;
    float acc = 1.0f;
#pragma unroll
    for (int ic = 0; ic < NCHUNK2; ++ic)
        acc *= Q[ic * (BATCH * OUT_F) + g];
    out[g] = 1.0f - acc;
}

extern "C" void kernel_launch(void* const* d_in, const int* in_sizes, int n_in,
                              void* d_out, int out_size, void* d_ws, size_t ws_size,
                              hipStream_t stream) {
    const float* x  = (const float*)d_in[0];
    const float* w1 = (const float*)d_in[1];
    const float* s1 = (const float*)d_in[2];
    const float* w2 = (const float*)d_in[3];
    float* out = (float*)d_out;

    // ws layout (floats): xt 128K | ht 128K | AC 2M | w2s 512K | P 4M | Q 2M
    float* xt  = (float*)d_ws;
    float* ht  = xt + (size_t)IN_F * BATCH;
    float* AC  = ht + (size_t)HID_F * BATCH;
    float* w2s = AC + (size_t)2 * IN_F * HID_F;
    float* P   = w2s + (size_t)HID_F * OUT_F;
    float* Q   = P + (size_t)NCHUNK1 * BATCH * HID_F;

    kPre<<<1664, 256, 0, stream>>>(x, w1, s1, w2, xt, AC, w2s);
    k1_layer1<<<dim3(HID_F / 256, BATCH / 32, NCHUNK1), 256, 0, stream>>>(AC, xt, P);
    k2_combine_h<<<dim3(HID_F / 32, BATCH / 32), 256, 0, stream>>>(P, ht);
    k3_layer2<<<dim3(OUT_F / 256, BATCH / 16, NCHUNK2), 256, 0, stream>>>(w2s, ht, Q);
    k4_final<<<(BATCH * OUT_F) / 256, 256, 0, stream>>>(Q, out);
}

// Round 3
// 65.482 us; speedup vs baseline: 1.1887x; 1.0407x over previous
//
#include <hip/hip_runtime.h>

#define IN_F  1024
#define HID_F 1024
#define OUT_F 512
#define BATCH 128
#define NCHUNK1 32   // i-chunks for layer 1 (chunk = 32 i)
#define NCHUNK2 32   // j-chunks for layer 2 (chunk = 32 j)
#define BT1 16       // batch tile per block, layer 1
#define BT2 8        // batch tile per block, layer 2

__device__ __forceinline__ float sigm(float v) {
    return 1.0f / (1.0f + __expf(-v));
}

// kPre: fused preprocessing.
//  blocks [0,1024):    AC[i][j] = (A,C) interleaved; A=1-w*s, C=w*(2s-1)
//  blocks [1024,1536): w2s = sigm(w2)
//  blocks [1536,1664): transpose x[128][1024] -> xt[1024][128]
__global__ __launch_bounds__(256) void kPre(const float* __restrict__ x,
                                            const float* __restrict__ w1,
                                            const float* __restrict__ s1,
                                            const float* __restrict__ w2,
                                            float* __restrict__ xt,
                                            float* __restrict__ AC,
                                            float* __restrict__ w2s) {
    const int bx = blockIdx.x;
    const int tid = threadIdx.x;
    if (bx < 1024) {
        const int e = (bx * 256 + tid) * 4;
        const float4 wv = *(const float4*)(w1 + e);
        const float4 sv = *(const float4*)(s1 + e);
        float w0 = sigm(wv.x), s0 = sigm(sv.x);
        float w1_ = sigm(wv.y), s1_ = sigm(sv.y);
        float w2_ = sigm(wv.z), s2_ = sigm(sv.z);
        float w3 = sigm(wv.w), s3 = sigm(sv.w);
        float4 lo, hi;
        lo.x = 1.0f - w0 * s0;  lo.y = w0 * (2.0f * s0 - 1.0f);
        lo.z = 1.0f - w1_ * s1_; lo.w = w1_ * (2.0f * s1_ - 1.0f);
        hi.x = 1.0f - w2_ * s2_; hi.y = w2_ * (2.0f * s2_ - 1.0f);
        hi.z = 1.0f - w3 * s3;  hi.w = w3 * (2.0f * s3 - 1.0f);
        *(float4*)(AC + 2 * e) = lo;
        *(float4*)(AC + 2 * e + 4) = hi;
    } else if (bx < 1536) {
        const int e = ((bx - 1024) * 256 + tid) * 4;
        const float4 wv = *(const float4*)(w2 + e);
        float4 r;
        r.x = sigm(wv.x); r.y = sigm(wv.y); r.z = sigm(wv.z); r.w = sigm(wv.w);
        *(float4*)(w2s + e) = r;
    } else {
        __shared__ float tile[32][33];
        const int bt = bx - 1536;
        const int i0 = (bt & 31) * 32;
        const int b0 = (bt >> 5) * 32;
        const int tx = tid & 31;
        const int ty = tid >> 5;   // 0..7
#pragma unroll
        for (int r = 0; r < 32; r += 8)
            tile[ty + r][tx] = x[(b0 + ty + r) * IN_F + i0 + tx];
        __syncthreads();
#pragma unroll
        for (int r = 0; r < 32; r += 8)
            xt[(i0 + ty + r) * BATCH + b0 + tx] = tile[tx][ty + r];
    }
}

// K1: layer-1 partial products over an i-chunk of 32.
// grid (4 j-tiles, 8 b-tiles(16), 32 i-chunks) = 1024 blocks, lane -> j coalesced.
__global__ __launch_bounds__(256, 4) void k1_layer1(const float* __restrict__ AC,
                                                    const float* __restrict__ xt,
                                                    float* __restrict__ P) {
    const int j  = blockIdx.x * 256 + threadIdx.x;
    const int b0 = blockIdx.y * BT1;
    const int i0 = blockIdx.z * (IN_F / NCHUNK1);
    float acc[BT1];
#pragma unroll
    for (int b = 0; b < BT1; ++b) acc[b] = 1.0f;
#pragma unroll 4
    for (int ii = 0; ii < IN_F / NCHUNK1; ++ii) {
        const int i = i0 + ii;
        const float2 ac = *(const float2*)(AC + 2 * (i * HID_F + j));
        const float* __restrict__ xr = xt + i * BATCH + b0;  // wave-uniform -> s_load
#pragma unroll
        for (int b = 0; b < BT1; ++b)
            acc[b] *= fmaf(xr[b], ac.y, ac.x);
    }
    float* Pp = P + blockIdx.z * (BATCH * HID_F) + b0 * HID_F + j;
#pragma unroll
    for (int b = 0; b < BT1; ++b)
        Pp[b * HID_F] = acc[b];
}

// K2: combine NCHUNK1 partial products -> h, stored transposed ht[j][b].
// grid (32 j-tiles, 4 b-tiles), block (32,8).
__global__ __launch_bounds__(256) void k2_combine_h(const float* __restrict__ P,
                                                    float* __restrict__ ht) {
    __shared__ float tile[32][33];
    const int j0 = blockIdx.x * 32;
    const int b0 = blockIdx.y * 32;
    const int tx = threadIdx.x & 31;
    const int ty = threadIdx.x >> 5;  // 0..7
#pragma unroll
    for (int r = 0; r < 32; r += 8) {
        const int b = b0 + ty + r;
        float acc = 1.0f;
#pragma unroll
        for (int ic = 0; ic < NCHUNK1; ++ic)
            acc *= P[ic * (BATCH * HID_F) + b * HID_F + j0 + tx];
        tile[ty + r][tx] = acc;
    }
    __syncthreads();
#pragma unroll
    for (int r = 0; r < 32; r += 8)
        ht[(j0 + ty + r) * BATCH + b0 + tx] = tile[tx][ty + r];
}

// K3: layer-2 partial products over a j-chunk of 32.
// grid (2 o-tiles, 16 b-tiles(8), 32 j-chunks) = 1024 blocks, lane -> o coalesced.
__global__ __launch_bounds__(256, 4) void k3_layer2(const float* __restrict__ w2s,
                                                    const float* __restrict__ ht,
                                                    float* __restrict__ Q) {
    const int o  = blockIdx.x * 256 + threadIdx.x;
    const int b0 = blockIdx.y * BT2;
    const int j0 = blockIdx.z * (HID_F / NCHUNK2);
    float acc[BT2];
#pragma unroll
    for (int b = 0; b < BT2; ++b) acc[b] = 1.0f;
#pragma unroll 4
    for (int jj = 0; jj < HID_F / NCHUNK2; ++jj) {
        const int j = j0 + jj;
        const float wv = w2s[j * OUT_F + o];
        const float* __restrict__ hr = ht + j * BATCH + b0;  // wave-uniform -> s_load
#pragma unroll
        for (int b = 0; b < BT2; ++b)
            acc[b] *= fmaf(-wv, hr[b], 1.0f);
    }
    float* Qp = Q + blockIdx.z * (BATCH * OUT_F) + b0 * OUT_F + o;
#pragma unroll
    for (int b = 0; b < BT2; ++b)
        Qp[b * OUT_F] = acc[b];
}

// K4: final combine: out[b,o] = 1 - prod_chunks Q
__global__ __launch_bounds__(256) void k4_final(const float* __restrict__ Q,
                                                float* __restrict__ out) {
    const int g = blockIdx.x * 256 + threadIdx.x;
    float acc = 1.0f;
#pragma unroll
    for (int ic = 0; ic < NCHUNK2; ++ic)
        acc *= Q[ic * (BATCH * OUT_F) + g];
    out[g] = 1.0f - acc;
}

extern "C" void kernel_launch(void* const* d_in, const int* in_sizes, int n_in,
                              void* d_out, int out_size, void* d_ws, size_t ws_size,
                              hipStream_t stream) {
    const float* x  = (const float*)d_in[0];
    const float* w1 = (const float*)d_in[1];
    const float* s1 = (const float*)d_in[2];
    const float* w2 = (const float*)d_in[3];
    float* out = (float*)d_out;

    // ws layout (floats): xt 128K | ht 128K | AC 2M | w2s 512K | P 4M | Q 2M
    float* xt  = (float*)d_ws;
    float* ht  = xt + (size_t)IN_F * BATCH;
    float* AC  = ht + (size_t)HID_F * BATCH;
    float* w2s = AC + (size_t)2 * IN_F * HID_F;
    float* P   = w2s + (size_t)HID_F * OUT_F;
    float* Q   = P + (size_t)NCHUNK1 * BATCH * HID_F;

    kPre<<<1664, 256, 0, stream>>>(x, w1, s1, w2, xt, AC, w2s);
    k1_layer1<<<dim3(HID_F / 256, BATCH / BT1, NCHUNK1), 256, 0, stream>>>(AC, xt, P);
    k2_combine_h<<<dim3(HID_F / 32, BATCH / 32), 256, 0, stream>>>(P, ht);
    k3_layer2<<<dim3(OUT_F / 256, BATCH / BT2, NCHUNK2), 256, 0, stream>>>(w2s, ht, Q);
    k4_final<<<(BATCH * OUT_F) / 256, 256, 0, stream>>>(Q, out);
}